// Round 1
// baseline (1299.851 us; speedup 1.0000x reference)
//
#include <hip/hip_runtime.h>
#include <math.h>

#define NEXP 32
#define DIM  2048

// ---------------------------------------------------------------------------
// k_logits: one block per expert. logits[e] = dot(vin, Gw[e,:]) + Gb[e]
// grid = NEXP, block = 256
// ---------------------------------------------------------------------------
__global__ void k_logits(const float* __restrict__ vin,
                         const float* __restrict__ Gw,
                         const float* __restrict__ Gb,
                         float* __restrict__ logits) {
    const int e = blockIdx.x;
    const int t = threadIdx.x;
    const float4* __restrict__ row4 = (const float4*)(Gw + (size_t)e * DIM);
    const float4* __restrict__ v4   = (const float4*)vin;

    float p = 0.f;
    // DIM/4 = 512 float4; 256 threads -> 2 each, coalesced
    #pragma unroll
    for (int it = 0; it < 2; ++it) {
        const int idx = t + it * 256;
        const float4 a = v4[idx];
        const float4 w = row4[idx];
        p += a.x * w.x + a.y * w.y + a.z * w.z + a.w * w.w;
    }
    // wave reduce (64 lanes)
    #pragma unroll
    for (int off = 32; off; off >>= 1) p += __shfl_down(p, off);

    __shared__ float s[4];
    const int wid = t >> 6, lane = t & 63;
    if (lane == 0) s[wid] = p;
    __syncthreads();
    if (t == 0) logits[e] = s[0] + s[1] + s[2] + s[3] + Gb[e];
}

// ---------------------------------------------------------------------------
// k_stage: block b computes vout[h=b] = sum_e gate[e] * act(dot(vin, W[e,h,:]) + b[e,h])
// gate = softmax(logits) computed redundantly per thread (cheap, cached loads).
// 4 waves/block; wave w handles experts w*8 .. w*8+7.
// grid = DIM, block = 256
// ---------------------------------------------------------------------------
template <bool RELU>
__global__ void k_stage(const float* __restrict__ vin,
                        const float* __restrict__ W,
                        const float* __restrict__ bias,
                        const float* __restrict__ logits,
                        float* __restrict__ vout) {
    const int h = blockIdx.x;
    const int t = threadIdx.x;
    const int wid = t >> 6, lane = t & 63;

    // softmax normalization terms over 32 logits (uniform, L1-cached loads)
    float m = -INFINITY;
    #pragma unroll
    for (int e = 0; e < NEXP; ++e) m = fmaxf(m, logits[e]);
    float ssum = 0.f;
    #pragma unroll
    for (int e = 0; e < NEXP; ++e) ssum += __expf(logits[e] - m);
    const float inv = 1.f / ssum;

    const float4* __restrict__ v4 = (const float4*)vin;

    float sacc = 0.f;  // meaningful on lane 0 only
    #pragma unroll
    for (int j = 0; j < 8; ++j) {
        const int e = wid * 8 + j;
        const float4* __restrict__ row4 =
            (const float4*)(W + ((size_t)e * DIM + (size_t)h) * DIM);
        float p = 0.f;
        // DIM/4 = 512 float4 over 64 lanes -> 8 iters, fully coalesced 1 KiB/instr
        #pragma unroll
        for (int it = 0; it < 8; ++it) {
            const float4 a = v4[lane + it * 64];
            const float4 w = row4[lane + it * 64];
            p += a.x * w.x + a.y * w.y + a.z * w.z + a.w * w.w;
        }
        #pragma unroll
        for (int off = 32; off; off >>= 1) p += __shfl_down(p, off);
        if (lane == 0) {
            float v = p + bias[(size_t)e * DIM + h];
            if (RELU) v = fmaxf(v, 0.f);
            const float gate = __expf(logits[e] - m) * inv;
            sacc += gate * v;
        }
    }

    __shared__ float s[4];
    if (lane == 0) s[wid] = sacc;
    __syncthreads();
    if (t == 0) vout[h] = s[0] + s[1] + s[2] + s[3];
}

// ---------------------------------------------------------------------------
extern "C" void kernel_launch(void* const* d_in, const int* in_sizes, int n_in,
                              void* d_out, int out_size, void* d_ws, size_t ws_size,
                              hipStream_t stream) {
    const float* x   = (const float*)d_in[0];
    const float* G1w = (const float*)d_in[1];
    const float* G1b = (const float*)d_in[2];
    const float* G2w = (const float*)d_in[3];
    const float* G2b = (const float*)d_in[4];
    const float* G3w = (const float*)d_in[5];
    const float* G3b = (const float*)d_in[6];
    const float* W1  = (const float*)d_in[7];
    const float* b1  = (const float*)d_in[8];
    const float* W2  = (const float*)d_in[9];
    const float* b2  = (const float*)d_in[10];
    const float* W3  = (const float*)d_in[11];
    const float* b3  = (const float*)d_in[12];

    float* out = (float*)d_out;
    float* ws  = (float*)d_ws;

    float* lg1 = ws;
    float* lg2 = ws + 32;
    float* lg3 = ws + 64;
    float* h1  = ws + 256;
    float* h2  = ws + 256 + DIM;

    k_logits<<<NEXP, 256, 0, stream>>>(x, G1w, G1b, lg1);
    k_stage<true ><<<DIM, 256, 0, stream>>>(x,  W1, b1, lg1, h1);
    k_logits<<<NEXP, 256, 0, stream>>>(h1, G2w, G2b, lg2);
    k_stage<true ><<<DIM, 256, 0, stream>>>(h1, W2, b2, lg2, h2);
    k_logits<<<NEXP, 256, 0, stream>>>(h2, G3w, G3b, lg3);
    k_stage<false><<<DIM, 256, 0, stream>>>(h2, W3, b3, lg3, out);
}